// Round 1
// baseline (1243.932 us; speedup 1.0000x reference)
//
#include <hip/hip_runtime.h>

#define NF 16
#define EMBED 32
#define EQ 8               // EMBED/4 float4s per embedding row
#define FIELD_DIM 31250
#define VOCAB 500000       // NF * FIELD_DIM
#define NPAIRS 120
#define BATCH 16384

// Packed (i<<4)|j for the 120 upper-triangular pairs, row-major (numpy triu_indices order)
__constant__ unsigned char c_pairs[NPAIRS] = {
    0x01,0x02,0x03,0x04,0x05,0x06,0x07,0x08,0x09,0x0A,0x0B,0x0C,0x0D,0x0E,0x0F,
    0x12,0x13,0x14,0x15,0x16,0x17,0x18,0x19,0x1A,0x1B,0x1C,0x1D,0x1E,0x1F,
    0x23,0x24,0x25,0x26,0x27,0x28,0x29,0x2A,0x2B,0x2C,0x2D,0x2E,0x2F,
    0x34,0x35,0x36,0x37,0x38,0x39,0x3A,0x3B,0x3C,0x3D,0x3E,0x3F,
    0x45,0x46,0x47,0x48,0x49,0x4A,0x4B,0x4C,0x4D,0x4E,0x4F,
    0x56,0x57,0x58,0x59,0x5A,0x5B,0x5C,0x5D,0x5E,0x5F,
    0x67,0x68,0x69,0x6A,0x6B,0x6C,0x6D,0x6E,0x6F,
    0x78,0x79,0x7A,0x7B,0x7C,0x7D,0x7E,0x7F,
    0x89,0x8A,0x8B,0x8C,0x8D,0x8E,0x8F,
    0x9A,0x9B,0x9C,0x9D,0x9E,0x9F,
    0xAB,0xAC,0xAD,0xAE,0xAF,
    0xBC,0xBD,0xBE,0xBF,
    0xCD,0xCE,0xCF,
    0xDE,0xDF,
    0xEF
};

// One block per sample. 256 threads cover 960 (pair, d-quad) work items in 4 strided steps.
__global__ __launch_bounds__(256) void ffm_kernel(
    const int* __restrict__ x,
    const float4* __restrict__ W4,
    float4* __restrict__ out4)
{
    const int b = blockIdx.x;
    const int t = threadIdx.x;

    __shared__ int s_idx[NF];   // vocab-local index (field offset folded in)
    if (t < NF) {
        s_idx[t] = x[b * NF + t] + t * FIELD_DIM;
    }
    __syncthreads();

    float4* ob = out4 + (size_t)b * (NPAIRS * EQ);

    #pragma unroll
    for (int step = 0; step < 4; ++step) {
        int w = t + step * 256;            // 0..959 (last step: threads 192..255 idle)
        if (w < NPAIRS * EQ) {
            int p = w >> 3;                // pair index
            int q = w & 7;                 // float4 index within the 32-wide embed row
            int pk = c_pairs[p];
            int i = pk >> 4;
            int j = pk & 15;
            size_t ra = (size_t)j * (VOCAB * EQ) + (size_t)s_idx[i] * EQ + q; // W[j, idx_i, 4q..]
            size_t rb = (size_t)i * (VOCAB * EQ) + (size_t)s_idx[j] * EQ + q; // W[i, idx_j, 4q..]
            float4 a  = W4[ra];
            float4 bb = W4[rb];
            float4 r;
            r.x = a.x * bb.x;
            r.y = a.y * bb.y;
            r.z = a.z * bb.z;
            r.w = a.w * bb.w;
            ob[w] = r;
        }
    }
}

extern "C" void kernel_launch(void* const* d_in, const int* in_sizes, int n_in,
                              void* d_out, int out_size, void* d_ws, size_t ws_size,
                              hipStream_t stream) {
    const int*    x = (const int*)d_in[0];
    const float4* W = (const float4*)d_in[1];
    float4*     out = (float4*)d_out;

    ffm_kernel<<<BATCH, 256, 0, stream>>>(x, W, out);
}